// Round 12
// baseline (792.958 us; speedup 1.0000x reference)
//
#include <hip/hip_runtime.h>
#include <math.h>

// Model constants: B=32, T=50000, P=100, D=512, H=16, L=6, C=256
// SCALES=[1,2,4], HS=5 heads/scale, KD=32, N=500 patches, FF=2048, EPS=1e-3.
//
// KEY INSIGHT (round 0, verified): first layernorm is over a size-1 axis ->
// output == ln_in_b[0] everywhere. h is batch-independent; network runs once
// on (500 x 512); final row broadcast x32.
//
// Ledger: R6 bf16-MFMA. R7/8 k-splits 999->839. R10 branch-free 965 (on
// fused). R12 splits+branch-free 803. R13 deeper splits 797. R14 attn
// staging fusion 1024 (read amp). R15 wo_combine 881 (+84, dead concept).
// R16 attn 64-key split 783 (best).
// Round 17 (this round): ALGEBRAIC fusion — upsample/concat commutes with
// right-multiply, so comb = sum_s upsample(o_s) @ (Wo_s@Wc_s) + (bc +
// sum_s bo_s@Wc_s). Precompute W2c (batched MFMA, z=18, K-padded to 192
// with zero rows) + bconst once; DELETE wo_all (-6 dispatches, -0.14GF/l);
// comb becomes gather-GEMM over oAll, K=480 (padded 576, 9x64 chunks,
// row>>si does the upsample in addressing). Per-layer GEMM FLOPs
// 0.93 -> 0.25 GF.

#define DD 512
#define NN 500
#define HSC 5
#define KDD 32
#define QKVN 160
#define QKV3 480
#define FF 2048
#define NL 6
#define NC 256
#define NB 32
#define LNEPS 1e-3f
#define BM 128
#define BN 64
#define KCHB 64

// total attn rows over scales (500+250+125)
#define RTOT 875
#define OSZ 140000      // RTOT*160
#define MLSZ 4384       // RTOT*5 rounded up
#define QSP 420000      // qkv partial slice stride (floats)
#define W2CL 98304      // per-(l,s) W2c block: 192*512

typedef __attribute__((ext_vector_type(8))) short bf16x8;
typedef __attribute__((ext_vector_type(4))) float f32x4;

__device__ __forceinline__ float gelu_exact(float x) {
    return 0.5f * x * (1.0f + erff(x * 0.70710678118654752f));
}

// pack two f32 -> two bf16 (RNE) in one instr
__device__ __forceinline__ unsigned int pkbf(float a, float b) {
    unsigned int r;
    asm("v_cvt_pk_bf16_f32 %0, %1, %2" : "=v"(r) : "v"(a), "v"(b));
    return r;
}

// ======================= MFMA GEMM core =======================
// Tile: BM=128 x BN=64, 256 threads = 4 waves (2x2), K-chunk 64.
// A fp32 [M][K] (lda), POOL row-pooling (compile-time);
// B fp32 [K][N]: caller resolves per-thread column -> Bcol (always valid).
// ALL loads unconditional/branch-free: rows clamped to M-1 (dup rows never
// stored); TAIL>0: addresses clamped to klim, tail values masked via
// cndmask (A side only; B garbage x A-zero = 0).
// LDS row pitch 128B, swizzle byte ^= ((row&7)<<4) -> conflict-free b128.

template<int POOL, int TAIL>
__device__ __forceinline__ void mstage(
        const float* __restrict__ A, int lda,
        const float* __restrict__ Bcol, int ldb,
        int M, int bm, int k0, int klim,
        int ar4, int akq, int bkq,
        float4 (&aR)[2][4], float4 (&bR)[4]) {
    #pragma unroll
    for (int p = 0; p < 2; ++p) {
        int row = min(bm + ar4 + p * 64, M - 1);
        const float* ap = A + (size_t)row * POOL * lda;
        #pragma unroll
        for (int i = 0; i < 4; ++i) {
            int kk = akq + i * 4;
            int kg = TAIL ? min(k0 + kk, klim - 4) : (k0 + kk);
            float4 v = *(const float4*)(ap + kg);
            #pragma unroll
            for (int t = 1; t < POOL; ++t) {
                float4 u = *(const float4*)(ap + kg + (size_t)t * lda);
                v.x += u.x; v.y += u.y; v.z += u.z; v.w += u.w;
            }
            if (POOL > 1) {
                const float ip = 1.0f / (float)POOL;
                v.x *= ip; v.y *= ip; v.z *= ip; v.w *= ip;
            }
            if (TAIL) {
                bool ok = (k0 + kk) < klim;       // cndmask, no branch
                v.x = ok ? v.x : 0.f; v.y = ok ? v.y : 0.f;
                v.z = ok ? v.z : 0.f; v.w = ok ? v.w : 0.f;
            }
            aR[p][i] = v;
        }
    }
    #pragma unroll
    for (int i = 0; i < 4; ++i) {
        int kr = TAIL ? min(k0 + bkq + i, klim - 1) : (k0 + bkq + i);
        bR[i] = *(const float4*)(Bcol + (size_t)kr * ldb);
    }
}

// shared chunk body: regs -> LDS (bf16, swizzled), then 16 MFMA
#define CHUNK_LDS_WRITE() { \
    _Pragma("unroll") \
    for (int p = 0; p < 2; ++p) { \
        int r = ar4 + p * 64; \
        int swz = (r & 7) << 4; \
        char* base = (char*)As + r * 128; \
        _Pragma("unroll") \
        for (int i = 0; i < 4; ++i) { \
            int cb = (akq + i * 4) * 2; \
            *(uint2*)(base + (cb ^ swz)) = make_uint2( \
                pkbf(aR[p][i].x, aR[p][i].y), pkbf(aR[p][i].z, aR[p][i].w)); \
        } \
    } \
    { \
        const float* b0 = (const float*)&bR[0]; \
        const float* b1 = (const float*)&bR[1]; \
        const float* b2 = (const float*)&bR[2]; \
        const float* b3 = (const float*)&bR[3]; \
        _Pragma("unroll") \
        for (int j = 0; j < 4; ++j) { \
            int nrow = bn4 * 4 + j; \
            char* base = (char*)Bs + nrow * 128; \
            *(uint2*)(base + ((bkq * 2) ^ ((nrow & 7) << 4))) = make_uint2( \
                pkbf(b0[j], b1[j]), pkbf(b2[j], b3[j])); \
        } \
    } }

#define CHUNK_MFMA() { \
    _Pragma("unroll") \
    for (int half = 0; half < 2; ++half) { \
        const int kb = (half * 32 + (lane >> 4) * 8) * 2; \
        bf16x8 af[4], bf[2]; \
        _Pragma("unroll") \
        for (int m = 0; m < 4; ++m) { \
            int r = wm * 64 + m * 16 + (lane & 15); \
            af[m] = *(const bf16x8*)((const char*)As + r * 128 + (kb ^ ((r & 7) << 4))); \
        } \
        _Pragma("unroll") \
        for (int n = 0; n < 2; ++n) { \
            int r = wn * 32 + n * 16 + (lane & 15); \
            bf[n] = *(const bf16x8*)((const char*)Bs + r * 128 + (kb ^ ((r & 7) << 4))); \
        } \
        _Pragma("unroll") \
        for (int m = 0; m < 4; ++m) \
            _Pragma("unroll") \
            for (int n = 0; n < 2; ++n) \
                acc[m][n] = __builtin_amdgcn_mfma_f32_16x16x32_bf16( \
                    af[m], bf[n], acc[m][n], 0, 0, 0); \
    } }

template<int POOL, int TAIL>
__device__ __forceinline__ void mfma_core(
        const float* __restrict__ A, int lda,
        const float* __restrict__ Bcol, int ldb,
        int M, int bm, int ks, int nch, int klim, f32x4 (&acc)[4][2]) {
    __shared__ __align__(16) unsigned short As[128 * 64];   // 16 KB
    __shared__ __align__(16) unsigned short Bs[64 * 64];    // 8 KB
    const int tid = threadIdx.x;
    const int ar4 = tid >> 2, akq = (tid & 3) * 16;
    const int bkq = (tid >> 4) * 4, bn4 = tid & 15;
    const int lane = tid & 63, wid = tid >> 6;
    const int wm = wid >> 1, wn = wid & 1;

    float4 aR[2][4], bR[4];
    mstage<POOL, TAIL>(A, lda, Bcol, ldb, M, bm, ks, klim,
                       ar4, akq, bkq, aR, bR);

    for (int c = 0; c < nch; ++c) {
        __syncthreads();
        CHUNK_LDS_WRITE();
        __syncthreads();
        if (c + 1 < nch)
            mstage<POOL, TAIL>(A, lda, Bcol, ldb, M, bm,
                               ks + (c + 1) * KCHB, klim,
                               ar4, akq, bkq, aR, bR);
        CHUNK_MFMA();
    }
}

#define MACC_INIT(acc) { _Pragma("unroll") for (int m_ = 0; m_ < 4; ++m_) \
    _Pragma("unroll") for (int n_ = 0; n_ < 2; ++n_) \
    _Pragma("unroll") for (int j_ = 0; j_ < 4; ++j_) acc[m_][n_][j_] = 0.f; }

// ======================= setup =======================
__global__ void colsum_kernel(const float* __restrict__ pw, float* __restrict__ csum) {
    int d = blockIdx.x * blockDim.x + threadIdx.x;
    if (d < DD) {
        float s = 0.f;
        for (int p = 0; p < 100; ++p) s += pw[p * DD + d];
        csum[d] = s;
    }
}

__global__ void init_h(const float* __restrict__ csum, const float* __restrict__ pb,
                       const float* __restrict__ pos, const float* __restrict__ lnb,
                       float* __restrict__ h) {
    int idx = blockIdx.x * 256 + threadIdx.x;
    if (idx >= NN * DD) return;
    int d = idx & (DD - 1);
    h[idx] = lnb[0] * csum[d] + pb[d] + pos[idx];
}

// ======================= W2c precompute (once) =============================
// W2c[l,s] = Wo[l,s] (160x512) @ Wc[l][s*512:(s+1)*512] (512x512),
// stored as (l,s,192,512) with rows 160..191 = 0 (K padding for comb).
// grid (8, 2, 18): z = l*3+s.
__global__ __launch_bounds__(256, 2) void w2c_pre(
        const float* __restrict__ Wo, const float* __restrict__ Wc,
        float* __restrict__ w2c) {
    int z = blockIdx.z;
    int l = z / 3, s = z - l * 3;
    int bm = blockIdx.y * BM, bn = blockIdx.x * BN;
    int tid = threadIdx.x;
    const float* A = Wo + (size_t)z * QKVN * DD;
    const float* Bcol = Wc + (size_t)l * 1536 * DD + (size_t)s * DD * DD
                      + bn + (tid & 15) * 4;
    f32x4 acc[4][2];
    MACC_INIT(acc);
    mfma_core<1, 0>(A, DD, Bcol, DD, QKVN, bm, 0, 8, DD, acc);

    float* C = w2c + (size_t)z * W2CL;
    int lane = tid & 63, wid = tid >> 6, wm = wid >> 1, wn = wid & 1;
    #pragma unroll
    for (int q = 0; q < 2; ++q) {
        int c2 = bn + wn * 32 + q * 16 + (lane & 15);
        #pragma unroll
        for (int m = 0; m < 4; ++m) {
            int r0 = bm + wm * 64 + m * 16 + ((lane >> 4) << 2);
            #pragma unroll
            for (int j = 0; j < 4; ++j) {
                int r = r0 + j;
                if (r < QKVN) C[(size_t)r * DD + c2] = acc[m][q][j];
                else if (r < 192) C[(size_t)r * DD + c2] = 0.f;
            }
        }
    }
}

// bconst[l] = bc[l] + sum_s bo[l,s] @ Wc[l][s*512:...]  (once; grid NL x 512)
__global__ void bconst_pre(const float* __restrict__ bo, const float* __restrict__ Wc,
                           const float* __restrict__ bc, float* __restrict__ bconst) {
    int l = blockIdx.x, d = threadIdx.x;
    float acc = bc[(size_t)l * DD + d];
    for (int s = 0; s < 3; ++s) {
        const float* bp = bo + (size_t)(l * 3 + s) * DD;
        const float* wp = Wc + (size_t)l * 1536 * DD + (size_t)s * DD * DD + d;
        for (int j = 0; j < DD; ++j)
            acc += bp[j] * wp[(size_t)j * DD];
    }
    bconst[(size_t)l * DD + d] = acc;
}

// ======================= QKV partial (all scales, k-split S=4) =============
__global__ __launch_bounds__(256, 2) void qkv_part(
        const float* __restrict__ h,
        const float* __restrict__ Wq, const float* __restrict__ Wk,
        const float* __restrict__ Wv,
        float* __restrict__ part, int l) {
    int scale = blockIdx.z >> 2, ps = blockIdx.z & 3;
    int n = NN >> scale;
    int bm = blockIdx.y * BM;
    if (bm >= n) return;
    int bn = blockIdx.x * BN;
    size_t w = (size_t)(l * 3 + scale);
    int tid = threadIdx.x;
    int col = min(bn + (tid & 15) * 4, QKV3 - 4);
    int which = (col >= 320) ? 2 : ((col >= 160) ? 1 : 0);
    const float* Wsel = (which == 0) ? Wq : ((which == 1) ? Wk : Wv);
    const float* Bcol = Wsel + w * DD * QKVN + (col - which * QKVN);
    float* outb = part + (size_t)ps * QSP
                + (scale == 0 ? 0 : (scale == 1 ? 240000 : 360000));

    f32x4 acc[4][2];
    MACC_INIT(acc);
    if (scale == 0)
        mfma_core<1, 0>(h, DD, Bcol, QKVN, n, bm, ps * 128, 2, DD, acc);
    else if (scale == 1)
        mfma_core<2, 0>(h, DD, Bcol, QKVN, n, bm, ps * 128, 2, DD, acc);
    else
        mfma_core<4, 0>(h, DD, Bcol, QKVN, n, bm, ps * 128, 2, DD, acc);

    int lane = tid & 63, wid = tid >> 6, wm = wid >> 1, wn = wid & 1;
    #pragma unroll
    for (int q = 0; q < 2; ++q) {
        int cb = bn + wn * 32 + q * 16;
        if (cb >= QKV3) continue;
        int c2 = cb + (lane & 15);
        #pragma unroll
        for (int m = 0; m < 4; ++m) {
            int r0 = bm + wm * 64 + m * 16 + ((lane >> 4) << 2);
            #pragma unroll
            for (int j = 0; j < 4; ++j) {
                int r = r0 + j;
                if (r < n) outb[(size_t)r * QKV3 + c2] = acc[m][q][j];
            }
        }
    }
}

__global__ void qkv_reduce(const float* __restrict__ part,
                           const float* __restrict__ bq,
                           const float* __restrict__ bk,
                           const float* __restrict__ bv,
                           float* __restrict__ qkvAll, int l) {
    int idx = blockIdx.x * 256 + threadIdx.x;
    if (idx >= 420000) return;
    int scale, base;
    if (idx < 240000) { scale = 0; base = 0; }
    else if (idx < 360000) { scale = 1; base = 240000; }
    else { scale = 2; base = 360000; }
    int rowrem = (idx - base) % QKV3;
    int which = rowrem / QKVN;
    int col = rowrem - which * QKVN;
    float v = part[idx] + part[QSP + idx]
            + part[2 * QSP + idx] + part[3 * QSP + idx];
    v += ((which == 0) ? bq : (which == 1 ? bk : bv))[(size_t)(l * 3 + scale) * QKVN + col];
    qkvAll[idx] = v;
}

// ======================= attention: 64-key-split flash =====================
__global__ __launch_bounds__(256, 2) void attn_split(
        const float* __restrict__ qkvAll, float* __restrict__ oPart,
        float* __restrict__ mPart, float* __restrict__ lPart) {
    int z = blockIdx.z;
    int scale, sp;
    if (z < 8)       { scale = 0; sp = z; }
    else if (z < 12) { scale = 1; sp = z - 8; }
    else             { scale = 2; sp = z - 12; }
    int n = NN >> scale;
    int qt = blockIdx.x;
    if (qt * 64 >= n) return;
    int hh = blockIdx.y;
    int ks = sp * 64;
    int ke = min(n, ks + 64);
    const float* qkv = qkvAll + (scale == 0 ? 0 : (scale == 1 ? 240000 : 360000));
    int rowb = (scale == 0 ? 0 : (scale == 1 ? 500 : 750));

    int tid = threadIdx.x;
    int kg = tid & 7, qq = tid >> 3;
    int q0 = qt * 64 + qq, q1 = q0 + 32;
    bool ok0 = q0 < n, ok1 = q1 < n;

    float qa[32], qb[32];
    {
        const float* p0 = qkv + (size_t)(ok0 ? q0 : 0) * QKV3 + hh * KDD;
        const float* p1 = qkv + (size_t)(ok1 ? q1 : 0) * QKV3 + hh * KDD;
        #pragma unroll
        for (int c4 = 0; c4 < 8; ++c4) {
            float4 v0 = *(const float4*)(p0 + c4 * 4);
            float4 v1 = *(const float4*)(p1 + c4 * 4);
            qa[c4 * 4] = v0.x; qa[c4 * 4 + 1] = v0.y; qa[c4 * 4 + 2] = v0.z; qa[c4 * 4 + 3] = v0.w;
            qb[c4 * 4] = v1.x; qb[c4 * 4 + 1] = v1.y; qb[c4 * 4 + 2] = v1.z; qb[c4 * 4 + 3] = v1.w;
        }
    }

    __shared__ float Ks[64][36];
    __shared__ float Vs[64][36];
    float o0[32], o1[32];
    #pragma unroll
    for (int c = 0; c < 32; ++c) { o0[c] = 0.f; o1[c] = 0.f; }
    float m0 = -1e30f, m1 = -1e30f, l0 = 0.f, l1 = 0.f;

    int srow = tid >> 2, scol = tid & 3;

    {
        int kc = ks;
        int krow = kc + srow;
        bool ok = krow < ke;
        const float* kp = qkv + (size_t)(ok ? krow : 0) * QKV3 + QKVN + hh * KDD;
        #pragma unroll
        for (int half = 0; half < 2; ++half) {
            int cc = (half * 4 + scol) * 4;
            float4 kv = ok ? *(const float4*)(kp + cc) : make_float4(0.f, 0.f, 0.f, 0.f);
            float4 vv = ok ? *(const float4*)(kp + QKVN + cc) : make_float4(0.f, 0.f, 0.f, 0.f);
            Ks[srow][cc] = kv.x; Ks[srow][cc + 1] = kv.y; Ks[srow][cc + 2] = kv.z; Ks[srow][cc + 3] = kv.w;
            Vs[srow][cc] = vv.x; Vs[srow][cc + 1] = vv.y; Vs[srow][cc + 2] = vv.z; Vs[srow][cc + 3] = vv.w;
        }
        __syncthreads();

        float p0[8], p1[8];
        float cm = -1e30f;
        #pragma unroll
        for (int jj = 0; jj < 8; ++jj) {
            int j = jj * 8 + kg;
            float s0 = 0.f, s1 = 0.f;
            #pragma unroll
            for (int c4 = 0; c4 < 8; ++c4) {
                float4 kv = *(const float4*)&Ks[j][c4 * 4];
                s0 += qa[c4 * 4] * kv.x + qa[c4 * 4 + 1] * kv.y
                    + qa[c4 * 4 + 2] * kv.z + qa[c4 * 4 + 3] * kv.w;
                s1 += qb[c4 * 4] * kv.x + qb[c4 * 4 + 1] * kv.y
                    + qb[c4 * 4 + 2] * kv.z + qb[c4 * 4 + 3] * kv.w;
            }
            s0 *= 0.17677669529663687f;
            s1 *= 0.17677669529663687f;
            if (kc + j >= ke) { s0 = -1e30f; s1 = -1e30f; }
            p0[jj] = s0; p1[jj] = s1;
            cm = fmaxf(cm, fmaxf(s0, s1));
        }
        cm = fmaxf(cm, __shfl_xor(cm, 1));
        cm = fmaxf(cm, __shfl_xor(cm, 2));
        cm = fmaxf(cm, __shfl_xor(cm, 4));

        m0 = cm; m1 = cm;
        #pragma unroll
        for (int jj = 0; jj < 8; ++jj) {
            p0[jj] = expf(p0[jj] - cm); l0 += p0[jj];
            p1[jj] = expf(p1[jj] - cm); l1 += p1[jj];
        }
        #pragma unroll
        for (int jj = 0; jj < 8; ++jj) {
            int j = jj * 8 + kg;
            float w0 = p0[jj], w1 = p1[jj];
            #pragma unroll
            for (int c4 = 0; c4 < 8; ++c4) {
                float4 vv = *(const float4*)&Vs[j][c4 * 4];
                o0[c4 * 4]     += w0 * vv.x; o0[c4 * 4 + 1] += w0 * vv.y;
                o0[c4 * 4 + 2] += w0 * vv.z; o0[c4 * 4 + 3] += w0 * vv.w;
                o1[c4 * 4]     += w1 * vv.x; o1[c4 * 4 + 1] += w1 * vv.y;
                o1[c4 * 4 + 2] += w1 * vv.z; o1[c4 * 4 + 3] += w1 * vv.w;
            }
        }
    }
    #pragma unroll
    for (int st = 1; st < 8; st <<= 1) {
        l0 += __shfl_xor(l0, st);
        l1 += __shfl_xor(l1, st);
        #pragma unroll
        for (int c = 0; c < 32; ++c) {
            o0[c] += __shfl_xor(o0[c], st);
            o1[c] += __shfl_xor(o1[c], st);
        }
    }
    if (kg == 0) {
        float* ob = oPart + (size_t)sp * OSZ;
        if (ok0) {
            int r = rowb + q0;
            float* op = ob + (size_t)r * QKVN + hh * KDD;
            #pragma unroll
            for (int c4 = 0; c4 < 8; ++c4) {
                float4 v; v.x = o0[c4*4]; v.y = o0[c4*4+1]; v.z = o0[c4*4+2]; v.w = o0[c4*4+3];
                *(float4*)(op + c4 * 4) = v;
            }
            mPart[sp * MLSZ + r * HSC + hh] = m0;
            lPart[sp * MLSZ + r * HSC + hh] = l0;
        }
        if (ok1) {
            int r = rowb + q1;
            float* op = ob + (size_t)r * QKVN + hh * KDD;
            #pragma unroll
            for (int c4 = 0; c4 < 8; ++c4) {
                float4 v; v.x = o1[c4*4]; v.y = o1[c4*4+1]; v.z = o1[c4*4+2]; v.w = o1[c4*4+3];
                *(float4*)(op + c4 * 4) = v;
            }
            mPart[sp * MLSZ + r * HSC + hh] = m1;
            lPart[sp * MLSZ + r * HSC + hh] = l1;
        }
    }
}

// ns = 8 >> scale partial slices; writes oAll at offsets 0/80000/120000
__global__ void attn_combine(const float* __restrict__ oPart,
                             const float* __restrict__ mPart,
                             const float* __restrict__ lPart,
                             float* __restrict__ oAll) {
    int idx = blockIdx.x * 256 + threadIdx.x;
    if (idx >= OSZ) return;
    int rh = idx >> 5;
    int r = rh / HSC, hh = rh - r * HSC;
    int scale = (r < 500) ? 0 : (r < 750 ? 1 : 2);
    int ns = 8 >> scale;
    float M = -1e30f;
    for (int s = 0; s < ns; ++s) M = fmaxf(M, mPart[s * MLSZ + r * HSC + hh]);
    float L = 0.f, val = 0.f;
    for (int s = 0; s < ns; ++s) {
        float wgt = expf(mPart[s * MLSZ + r * HSC + hh] - M);
        L += wgt * lPart[s * MLSZ + r * HSC + hh];
        val += wgt * oPart[(size_t)s * OSZ + idx];
    }
    oAll[idx] = val / L;
}

// ======================= comb via W2c (gather oAll, K=480 padded 576) ======
// grid (8, 4, 9): z = sp in [0,9): si = sp/3, 64-k chunk (sp%3) of the
// 192-padded per-scale K block. A row gather: row>>si (upsample-by-read).
// W2c rows 160..191 are zeros -> no A-side tail mask needed; A k-address
// clamped to 156 so duplicate (not OOB) elements pair with the zero rows.
__global__ __launch_bounds__(256, 2) void comb_gather(
        const float* __restrict__ oAll, const float* __restrict__ w2c,
        float* __restrict__ part, int l) {
    int sp = blockIdx.z;
    int si = (sp >= 6) ? 2 : (sp >= 3 ? 1 : 0);
    int kseg = (sp - si * 3) << 6;                 // 0,64,128
    int bm = blockIdx.y * BM, bn = blockIdx.x * BN;
    int tid = threadIdx.x;
    const int soff = (si == 0) ? 0 : (si == 1 ? 80000 : 120000);
    const float* Bcol = w2c + (size_t)(l * 3 + si) * W2CL
                      + (size_t)kseg * DD + bn + (tid & 15) * 4;

    __shared__ __align__(16) unsigned short As[128 * 64];
    __shared__ __align__(16) unsigned short Bs[64 * 64];
    const int ar4 = tid >> 2, akq = (tid & 3) * 16;
    const int bkq = (tid >> 4) * 4, bn4 = tid & 15;
    const int lane = tid & 63, wid = tid >> 6;
    const int wm = wid >> 1, wn = wid & 1;

    f32x4 acc[4][2];
    MACC_INIT(acc);
    float4 aR[2][4], bR[4];

    // single-chunk stage (branch-free)
    #pragma unroll
    for (int p = 0; p < 2; ++p) {
        int row = min(bm + ar4 + p * 64, NN - 1);
        const float* ap = oAll + soff + (size_t)(row >> si) * QKVN;
        #pragma unroll
        for (int i = 0; i < 4; ++i) {
            int kk = kseg + akq + i * 4;
            int kg2 = min(kk, QKVN - 4);           // clamp; pad rows of B are 0
            aR[p][i] = *(const float4*)(ap + kg2);
        }
    }
    #pragma unroll
    for (int i = 0; i < 4; ++i)
        bR[i] = *(const float4*)(Bcol + (size_t)(bkq + i) * DD);

    __syncthreads();
    CHUNK_LDS_WRITE();
    __syncthreads();
    CHUNK_MFMA();

    float* pz = part + (size_t)sp * NN * DD;
    #pragma unroll
    for (int q = 0; q < 2; ++q) {
        int c2 = bn + wn * 32 + q * 16 + (lane & 15);
        #pragma unroll
        for (int m = 0; m < 4; ++m) {
            int r0 = bm + wm * 64 + m * 16 + ((lane >> 4) << 2);
            #pragma unroll
            for (int j = 0; j < 4; ++j) {
                int r = r0 + j;
                if (r < NN) pz[(size_t)r * DD + c2] = acc[m][q][j];
            }
        }
    }
}

// ======================= W1 partial (k-split S=4) ==========================
__global__ __launch_bounds__(256, 2) void w1_part(
        const float* __restrict__ h, const float* __restrict__ W1,
        float* __restrict__ part) {
    int sp = blockIdx.z;
    int bm = blockIdx.y * BM, bn = blockIdx.x * BN;
    int tid = threadIdx.x;
    const float* Bcol = W1 + bn + (tid & 15) * 4;
    f32x4 acc[4][2];
    MACC_INIT(acc);
    mfma_core<1, 0>(h, DD, Bcol, FF, NN, bm, sp * 128, 2, DD, acc);

    float* pz = part + (size_t)sp * NN * FF;
    int lane = tid & 63, wid = tid >> 6, wm = wid >> 1, wn = wid & 1;
    #pragma unroll
    for (int q = 0; q < 2; ++q) {
        int c2 = bn + wn * 32 + q * 16 + (lane & 15);
        #pragma unroll
        for (int m = 0; m < 4; ++m) {
            int r0 = bm + wm * 64 + m * 16 + ((lane >> 4) << 2);
            #pragma unroll
            for (int j = 0; j < 4; ++j) {
                int r = r0 + j;
                if (r < NN) pz[(size_t)r * FF + c2] = acc[m][q][j];
            }
        }
    }
}

__global__ void w1_reduce(const float* __restrict__ part,
                          const float* __restrict__ b1, float* __restrict__ f) {
    int idx = blockIdx.x * 256 + threadIdx.x;
    if (idx >= NN * FF) return;
    float v = part[idx] + part[NN * FF + idx]
            + part[2 * NN * FF + idx] + part[3 * NN * FF + idx];
    f[idx] = gelu_exact(v + b1[idx & (FF - 1)]);
}

// ======================= W2 partial (k-split S=16) =========================
__global__ __launch_bounds__(256, 2) void w2_part(
        const float* __restrict__ f, const float* __restrict__ W2,
        float* __restrict__ part) {
    int sp = blockIdx.z;
    int bm = blockIdx.y * BM, bn = blockIdx.x * BN;
    int tid = threadIdx.x;
    const float* Bcol = W2 + bn + (tid & 15) * 4;
    f32x4 acc[4][2];
    MACC_INIT(acc);
    mfma_core<1, 0>(f, FF, Bcol, DD, NN, bm, sp * 128, 2, FF, acc);

    float* pz = part + (size_t)sp * NN * DD;
    int lane = tid & 63, wid = tid >> 6, wm = wid >> 1, wn = wid & 1;
    #pragma unroll
    for (int q = 0; q < 2; ++q) {
        int c2 = bn + wn * 32 + q * 16 + (lane & 15);
        #pragma unroll
        for (int m = 0; m < 4; ++m) {
            int r0 = bm + wm * 64 + m * 16 + ((lane >> 4) << 2);
            #pragma unroll
            for (int j = 0; j < 4; ++j) {
                int r = r0 + j;
                if (r < NN) pz[(size_t)r * DD + c2] = acc[m][q][j];
            }
        }
    }
}

// ======================= fused reduce + bias + residual + LN ===============
__global__ void reduce_add_ln(const float* __restrict__ part, int S,
                              const float* __restrict__ bias,
                              float* __restrict__ h,
                              const float* __restrict__ gw,
                              const float* __restrict__ bw) {
    int row = blockIdx.x, t = threadIdx.x;
    size_t idx = (size_t)row * DD + t;
    float x = h[idx] + bias[t];
    for (int s = 0; s < S; ++s) x += part[(size_t)s * NN * DD + idx];
    int lane = t & 63, wv = t >> 6;
    __shared__ float s1[8], s2[8];
    __shared__ float mb[2];
    float sum = x, sq = x * x;
    for (int off = 32; off; off >>= 1) {
        sum += __shfl_down(sum, off);
        sq  += __shfl_down(sq,  off);
    }
    if (lane == 0) { s1[wv] = sum; s2[wv] = sq; }
    __syncthreads();
    if (t == 0) {
        float a = 0.f, b = 0.f;
        for (int i = 0; i < 8; ++i) { a += s1[i]; b += s2[i]; }
        float mean = a / (float)DD;
        float var = b / (float)DD - mean * mean;
        mb[0] = mean;
        mb[1] = rsqrtf(var + LNEPS);
    }
    __syncthreads();
    h[idx] = (x - mb[0]) * mb[1] * gw[t] + bw[t];
}

// ======================= head =======================
__global__ void col_mean_part(const float* __restrict__ h, float* __restrict__ partial) {
    int col = blockIdx.x * 256 + threadIdx.x;
    int r0 = blockIdx.y * 20;
    float s = 0.f;
    #pragma unroll
    for (int r = 0; r < 20; ++r) s += h[(size_t)(r0 + r) * DD + col];
    partial[(size_t)blockIdx.y * DD + col] = s;
}

__global__ void head_kernel(const float* __restrict__ partial,
                            const float* __restrict__ hw,
                            const float* __restrict__ hb, float* __restrict__ out) {
    __shared__ float gs[DD];
    __shared__ float r[4];
    __shared__ float bmx, bsum;
    int t = threadIdx.x;
    for (int d = t; d < DD; d += 256) {
        float s = 0.f;
        #pragma unroll
        for (int p = 0; p < 25; ++p) s += partial[(size_t)p * DD + d];
        gs[d] = s / (float)NN;
    }
    __syncthreads();
    float acc = hb[t];
    #pragma unroll 16
    for (int d = 0; d < DD; ++d) acc += gs[d] * hw[(size_t)d * NC + t];
    int lane = t & 63, wv = t >> 6;
    float mx = acc;
    for (int off = 32; off; off >>= 1) mx = fmaxf(mx, __shfl_down(mx, off));
    if (lane == 0) r[wv] = mx;
    __syncthreads();
    if (t == 0) bmx = fmaxf(fmaxf(r[0], r[1]), fmaxf(r[2], r[3]));
    __syncthreads();
    float e = expf(acc - bmx);
    float s = e;
    for (int off = 32; off; off >>= 1) s += __shfl_down(s, off);
    if (lane == 0) r[wv] = s;
    __syncthreads();
    if (t == 0) bsum = 1.f / (r[0] + r[1] + r[2] + r[3]);
    __syncthreads();
    float pv = e * bsum;
    for (int b = 0; b < NB; ++b) out[(size_t)b * NC + t] = pv;
}

extern "C" void kernel_launch(void* const* d_in, const int* in_sizes, int n_in,
                              void* d_out, int out_size, void* d_ws, size_t ws_size,
                              hipStream_t stream) {
    const float* ln_in_b = (const float*)d_in[2];
    const float* patch_W = (const float*)d_in[3];
    const float* patch_b = (const float*)d_in[4];
    const float* pos_emb = (const float*)d_in[5];
    const float* Wq = (const float*)d_in[6];
    const float* bq = (const float*)d_in[7];
    const float* Wk = (const float*)d_in[8];
    const float* bk = (const float*)d_in[9];
    const float* Wv = (const float*)d_in[10];
    const float* bv = (const float*)d_in[11];
    const float* Wo = (const float*)d_in[12];
    const float* bo = (const float*)d_in[13];
    const float* Wc = (const float*)d_in[14];
    const float* bc = (const float*)d_in[15];
    const float* ln1_g = (const float*)d_in[16];
    const float* ln1_b = (const float*)d_in[17];
    const float* W1 = (const float*)d_in[18];
    const float* b1 = (const float*)d_in[19];
    const float* W2 = (const float*)d_in[20];
    const float* b2 = (const float*)d_in[21];
    const float* ln2_g = (const float*)d_in[22];
    const float* ln2_b = (const float*)d_in[23];
    const float* head_W = (const float*)d_in[24];
    const float* head_b = (const float*)d_in[25];
    float* out = (float*)d_out;

    // workspace (floats). part region aliases: qkvP (dead after qkv_reduce),
    // then oPart/mPart/lPart (dead after attn_combine), then comb/w1/w2
    // partials.
    float* ws = (float*)d_ws;
    float* h      = ws;                  // 256000
    float* csum   = h + 256000;          // 1024
    float* qkvAll = csum + 1024;         // 420000
    float* oAll   = qkvAll + 420000;     // 140000
    float* f      = oAll + 140000;       // 1024000
    float* part   = f + 1024000;         // 4194304
    float* headp  = part + 4194304;      // 12800
    float* w2c    = headp + 12800;       // 18*98304 = 1769472
    float* bconst = w2c + 1769472;       // 6*512 = 3072
    float* qkvP   = part;                // 4*420000 = 1680000
    float* oPart  = part + 1680000;      // 8*140000 = 1120000
    float* mPart  = oPart + 1120000;     // 8*4384
    float* lPart  = mPart + 8 * MLSZ;    // 8*4384

    colsum_kernel<<<1, 512, 0, stream>>>(patch_W, csum);
    init_h<<<(NN * DD + 255) / 256, 256, 0, stream>>>(csum, patch_b, pos_emb, ln_in_b, h);
    w2c_pre<<<dim3(8, 2, 18), 256, 0, stream>>>(Wo, Wc, w2c);
    bconst_pre<<<NL, DD, 0, stream>>>(bo, Wc, bc, bconst);

    for (int l = 0; l < NL; ++l) {
        qkv_part<<<dim3(8, 4, 12), 256, 0, stream>>>(h, Wq, Wk, Wv, qkvP, l);
        qkv_reduce<<<(420000 + 255) / 256, 256, 0, stream>>>(qkvP, bq, bk, bv, qkvAll, l);
        attn_split<<<dim3(8, HSC, 14), 256, 0, stream>>>(qkvAll, oPart, mPart, lPart);
        attn_combine<<<(OSZ + 255) / 256, 256, 0, stream>>>(oPart, mPart, lPart, oAll);
        comb_gather<<<dim3(8, 4, 9), 256, 0, stream>>>(oAll, w2c, part, l);
        reduce_add_ln<<<NN, DD, 0, stream>>>(part, 9, bconst + (size_t)l * DD, h,
                                             ln1_g + (size_t)l * DD, ln1_b + (size_t)l * DD);
        w1_part<<<dim3(32, 4, 4), 256, 0, stream>>>(
            h, W1 + (size_t)l * DD * FF, part);
        w1_reduce<<<(NN * FF + 255) / 256, 256, 0, stream>>>(
            part, b1 + (size_t)l * FF, f);
        w2_part<<<dim3(8, 4, 16), 256, 0, stream>>>(f, W2 + (size_t)l * FF * DD, part);
        reduce_add_ln<<<NN, DD, 0, stream>>>(part, 16, b2 + (size_t)l * DD, h,
                                             ln2_g + (size_t)l * DD, ln2_b + (size_t)l * DD);
    }
    col_mean_part<<<dim3(2, 25), 256, 0, stream>>>(h, headp);
    head_kernel<<<1, 256, 0, stream>>>(headp, head_W, head_b, out);
}

// Round 13
// 743.694 us; speedup vs baseline: 1.0662x; 1.0662x over previous
//
#include <hip/hip_runtime.h>
#include <math.h>

// Model constants: B=32, T=50000, P=100, D=512, H=16, L=6, C=256
// SCALES=[1,2,4], HS=5 heads/scale, KD=32, N=500 patches, FF=2048, EPS=1e-3.
//
// KEY INSIGHT (round 0, verified): first layernorm is over a size-1 axis ->
// output == ln_in_b[0] everywhere. h is batch-independent; network runs once
// on (500 x 512); final row broadcast x32.
//
// Ledger: R6 bf16-MFMA. R7/8 k-splits 999->839. R12 splits+branch-free 803.
// R13 deeper splits 797. R14 attn staging fusion 1024 (read amp). R15
// wo_combine 881. R16 attn 64-key split 783. R17 algebraic Wo@Wc fusion
// 793: fusion sound (absmax unchanged) but bconst_pre = 63us/iter (6
// blocks on 256 CUs, serial 1536-MAC loop) ate the whole wo_all saving.
// Round 18 (this round): parallelize bconst only. bconst_part: 144 blocks
// (18 z x 8 j-chunks), coalesced Wc reads, partials; bconst_fin: 6x512
// sums 24 partials + bc. ~63us -> ~6us. Everything else held from R17.

#define DD 512
#define NN 500
#define HSC 5
#define KDD 32
#define QKVN 160
#define QKV3 480
#define FF 2048
#define NL 6
#define NC 256
#define NB 32
#define LNEPS 1e-3f
#define BM 128
#define BN 64
#define KCHB 64

// total attn rows over scales (500+250+125)
#define RTOT 875
#define OSZ 140000      // RTOT*160
#define MLSZ 4384       // RTOT*5 rounded up
#define QSP 420000      // qkv partial slice stride (floats)
#define W2CL 98304      // per-(l,s) W2c block: 192*512

typedef __attribute__((ext_vector_type(8))) short bf16x8;
typedef __attribute__((ext_vector_type(4))) float f32x4;

__device__ __forceinline__ float gelu_exact(float x) {
    return 0.5f * x * (1.0f + erff(x * 0.70710678118654752f));
}

// pack two f32 -> two bf16 (RNE) in one instr
__device__ __forceinline__ unsigned int pkbf(float a, float b) {
    unsigned int r;
    asm("v_cvt_pk_bf16_f32 %0, %1, %2" : "=v"(r) : "v"(a), "v"(b));
    return r;
}

// ======================= MFMA GEMM core =======================
// Tile: BM=128 x BN=64, 256 threads = 4 waves (2x2), K-chunk 64.
// A fp32 [M][K] (lda), POOL row-pooling (compile-time);
// B fp32 [K][N]: caller resolves per-thread column -> Bcol (always valid).
// ALL loads unconditional/branch-free: rows clamped to M-1 (dup rows never
// stored); TAIL>0: addresses clamped to klim, tail values masked via
// cndmask (A side only; B garbage x A-zero = 0).
// LDS row pitch 128B, swizzle byte ^= ((row&7)<<4) -> conflict-free b128.

template<int POOL, int TAIL>
__device__ __forceinline__ void mstage(
        const float* __restrict__ A, int lda,
        const float* __restrict__ Bcol, int ldb,
        int M, int bm, int k0, int klim,
        int ar4, int akq, int bkq,
        float4 (&aR)[2][4], float4 (&bR)[4]) {
    #pragma unroll
    for (int p = 0; p < 2; ++p) {
        int row = min(bm + ar4 + p * 64, M - 1);
        const float* ap = A + (size_t)row * POOL * lda;
        #pragma unroll
        for (int i = 0; i < 4; ++i) {
            int kk = akq + i * 4;
            int kg = TAIL ? min(k0 + kk, klim - 4) : (k0 + kk);
            float4 v = *(const float4*)(ap + kg);
            #pragma unroll
            for (int t = 1; t < POOL; ++t) {
                float4 u = *(const float4*)(ap + kg + (size_t)t * lda);
                v.x += u.x; v.y += u.y; v.z += u.z; v.w += u.w;
            }
            if (POOL > 1) {
                const float ip = 1.0f / (float)POOL;
                v.x *= ip; v.y *= ip; v.z *= ip; v.w *= ip;
            }
            if (TAIL) {
                bool ok = (k0 + kk) < klim;       // cndmask, no branch
                v.x = ok ? v.x : 0.f; v.y = ok ? v.y : 0.f;
                v.z = ok ? v.z : 0.f; v.w = ok ? v.w : 0.f;
            }
            aR[p][i] = v;
        }
    }
    #pragma unroll
    for (int i = 0; i < 4; ++i) {
        int kr = TAIL ? min(k0 + bkq + i, klim - 1) : (k0 + bkq + i);
        bR[i] = *(const float4*)(Bcol + (size_t)kr * ldb);
    }
}

// shared chunk body: regs -> LDS (bf16, swizzled), then 16 MFMA
#define CHUNK_LDS_WRITE() { \
    _Pragma("unroll") \
    for (int p = 0; p < 2; ++p) { \
        int r = ar4 + p * 64; \
        int swz = (r & 7) << 4; \
        char* base = (char*)As + r * 128; \
        _Pragma("unroll") \
        for (int i = 0; i < 4; ++i) { \
            int cb = (akq + i * 4) * 2; \
            *(uint2*)(base + (cb ^ swz)) = make_uint2( \
                pkbf(aR[p][i].x, aR[p][i].y), pkbf(aR[p][i].z, aR[p][i].w)); \
        } \
    } \
    { \
        const float* b0 = (const float*)&bR[0]; \
        const float* b1 = (const float*)&bR[1]; \
        const float* b2 = (const float*)&bR[2]; \
        const float* b3 = (const float*)&bR[3]; \
        _Pragma("unroll") \
        for (int j = 0; j < 4; ++j) { \
            int nrow = bn4 * 4 + j; \
            char* base = (char*)Bs + nrow * 128; \
            *(uint2*)(base + ((bkq * 2) ^ ((nrow & 7) << 4))) = make_uint2( \
                pkbf(b0[j], b1[j]), pkbf(b2[j], b3[j])); \
        } \
    } }

#define CHUNK_MFMA() { \
    _Pragma("unroll") \
    for (int half = 0; half < 2; ++half) { \
        const int kb = (half * 32 + (lane >> 4) * 8) * 2; \
        bf16x8 af[4], bf[2]; \
        _Pragma("unroll") \
        for (int m = 0; m < 4; ++m) { \
            int r = wm * 64 + m * 16 + (lane & 15); \
            af[m] = *(const bf16x8*)((const char*)As + r * 128 + (kb ^ ((r & 7) << 4))); \
        } \
        _Pragma("unroll") \
        for (int n = 0; n < 2; ++n) { \
            int r = wn * 32 + n * 16 + (lane & 15); \
            bf[n] = *(const bf16x8*)((const char*)Bs + r * 128 + (kb ^ ((r & 7) << 4))); \
        } \
        _Pragma("unroll") \
        for (int m = 0; m < 4; ++m) \
            _Pragma("unroll") \
            for (int n = 0; n < 2; ++n) \
                acc[m][n] = __builtin_amdgcn_mfma_f32_16x16x32_bf16( \
                    af[m], bf[n], acc[m][n], 0, 0, 0); \
    } }

template<int POOL, int TAIL>
__device__ __forceinline__ void mfma_core(
        const float* __restrict__ A, int lda,
        const float* __restrict__ Bcol, int ldb,
        int M, int bm, int ks, int nch, int klim, f32x4 (&acc)[4][2]) {
    __shared__ __align__(16) unsigned short As[128 * 64];   // 16 KB
    __shared__ __align__(16) unsigned short Bs[64 * 64];    // 8 KB
    const int tid = threadIdx.x;
    const int ar4 = tid >> 2, akq = (tid & 3) * 16;
    const int bkq = (tid >> 4) * 4, bn4 = tid & 15;
    const int lane = tid & 63, wid = tid >> 6;
    const int wm = wid >> 1, wn = wid & 1;

    float4 aR[2][4], bR[4];
    mstage<POOL, TAIL>(A, lda, Bcol, ldb, M, bm, ks, klim,
                       ar4, akq, bkq, aR, bR);

    for (int c = 0; c < nch; ++c) {
        __syncthreads();
        CHUNK_LDS_WRITE();
        __syncthreads();
        if (c + 1 < nch)
            mstage<POOL, TAIL>(A, lda, Bcol, ldb, M, bm,
                               ks + (c + 1) * KCHB, klim,
                               ar4, akq, bkq, aR, bR);
        CHUNK_MFMA();
    }
}

#define MACC_INIT(acc) { _Pragma("unroll") for (int m_ = 0; m_ < 4; ++m_) \
    _Pragma("unroll") for (int n_ = 0; n_ < 2; ++n_) \
    _Pragma("unroll") for (int j_ = 0; j_ < 4; ++j_) acc[m_][n_][j_] = 0.f; }

// ======================= setup =======================
__global__ void colsum_kernel(const float* __restrict__ pw, float* __restrict__ csum) {
    int d = blockIdx.x * blockDim.x + threadIdx.x;
    if (d < DD) {
        float s = 0.f;
        for (int p = 0; p < 100; ++p) s += pw[p * DD + d];
        csum[d] = s;
    }
}

__global__ void init_h(const float* __restrict__ csum, const float* __restrict__ pb,
                       const float* __restrict__ pos, const float* __restrict__ lnb,
                       float* __restrict__ h) {
    int idx = blockIdx.x * 256 + threadIdx.x;
    if (idx >= NN * DD) return;
    int d = idx & (DD - 1);
    h[idx] = lnb[0] * csum[d] + pb[d] + pos[idx];
}

// ======================= W2c precompute (once) =============================
// W2c[l,s] = Wo[l,s] (160x512) @ Wc[l][s*512:(s+1)*512] (512x512),
// stored as (l,s,192,512) with rows 160..191 = 0 (K padding for comb).
// grid (8, 2, 18): z = l*3+s.
__global__ __launch_bounds__(256, 2) void w2c_pre(
        const float* __restrict__ Wo, const float* __restrict__ Wc,
        float* __restrict__ w2c) {
    int z = blockIdx.z;
    int l = z / 3, s = z - l * 3;
    int bm = blockIdx.y * BM, bn = blockIdx.x * BN;
    int tid = threadIdx.x;
    const float* A = Wo + (size_t)z * QKVN * DD;
    const float* Bcol = Wc + (size_t)l * 1536 * DD + (size_t)s * DD * DD
                      + bn + (tid & 15) * 4;
    f32x4 acc[4][2];
    MACC_INIT(acc);
    mfma_core<1, 0>(A, DD, Bcol, DD, QKVN, bm, 0, 8, DD, acc);

    float* C = w2c + (size_t)z * W2CL;
    int lane = tid & 63, wid = tid >> 6, wm = wid >> 1, wn = wid & 1;
    #pragma unroll
    for (int q = 0; q < 2; ++q) {
        int c2 = bn + wn * 32 + q * 16 + (lane & 15);
        #pragma unroll
        for (int m = 0; m < 4; ++m) {
            int r0 = bm + wm * 64 + m * 16 + ((lane >> 4) << 2);
            #pragma unroll
            for (int j = 0; j < 4; ++j) {
                int r = r0 + j;
                if (r < QKVN) C[(size_t)r * DD + c2] = acc[m][q][j];
                else if (r < 192) C[(size_t)r * DD + c2] = 0.f;
            }
        }
    }
}

// bconst partials: grid (18, 8): z = l*3+s, chunk of 64 j-rows.
// 256 threads: each handles 2 d-columns; Wc row reads coalesced.
__global__ void bconst_part(const float* __restrict__ bo,
                            const float* __restrict__ Wc,
                            float* __restrict__ bpart) {
    int z = blockIdx.x, ch = blockIdx.y;
    int l = z / 3, s = z - l * 3;
    int t = threadIdx.x;
    int j0 = ch * 64;
    const float* bp = bo + (size_t)z * DD + j0;
    const float* wp = Wc + (size_t)l * 1536 * DD + (size_t)s * DD * DD
                    + (size_t)j0 * DD;
    float a0 = 0.f, a1 = 0.f;
    for (int j = 0; j < 64; ++j) {
        float b = bp[j];
        a0 += b * wp[(size_t)j * DD + t];
        a1 += b * wp[(size_t)j * DD + t + 256];
    }
    float* op = bpart + ((size_t)z * 8 + ch) * DD;
    op[t] = a0;
    op[t + 256] = a1;
}

// bconst[l][d] = bc[l][d] + sum over 24 partials (3 scales x 8 chunks)
__global__ void bconst_fin(const float* __restrict__ bpart,
                           const float* __restrict__ bc,
                           float* __restrict__ bconst) {
    int l = blockIdx.x, d = threadIdx.x;
    float acc = bc[(size_t)l * DD + d];
    const float* bp = bpart + (size_t)l * 3 * 8 * DD;
    #pragma unroll
    for (int i = 0; i < 24; ++i) acc += bp[(size_t)i * DD + d];
    bconst[(size_t)l * DD + d] = acc;
}

// ======================= QKV partial (all scales, k-split S=4) =============
__global__ __launch_bounds__(256, 2) void qkv_part(
        const float* __restrict__ h,
        const float* __restrict__ Wq, const float* __restrict__ Wk,
        const float* __restrict__ Wv,
        float* __restrict__ part, int l) {
    int scale = blockIdx.z >> 2, ps = blockIdx.z & 3;
    int n = NN >> scale;
    int bm = blockIdx.y * BM;
    if (bm >= n) return;
    int bn = blockIdx.x * BN;
    size_t w = (size_t)(l * 3 + scale);
    int tid = threadIdx.x;
    int col = min(bn + (tid & 15) * 4, QKV3 - 4);
    int which = (col >= 320) ? 2 : ((col >= 160) ? 1 : 0);
    const float* Wsel = (which == 0) ? Wq : ((which == 1) ? Wk : Wv);
    const float* Bcol = Wsel + w * DD * QKVN + (col - which * QKVN);
    float* outb = part + (size_t)ps * QSP
                + (scale == 0 ? 0 : (scale == 1 ? 240000 : 360000));

    f32x4 acc[4][2];
    MACC_INIT(acc);
    if (scale == 0)
        mfma_core<1, 0>(h, DD, Bcol, QKVN, n, bm, ps * 128, 2, DD, acc);
    else if (scale == 1)
        mfma_core<2, 0>(h, DD, Bcol, QKVN, n, bm, ps * 128, 2, DD, acc);
    else
        mfma_core<4, 0>(h, DD, Bcol, QKVN, n, bm, ps * 128, 2, DD, acc);

    int lane = tid & 63, wid = tid >> 6, wm = wid >> 1, wn = wid & 1;
    #pragma unroll
    for (int q = 0; q < 2; ++q) {
        int cb = bn + wn * 32 + q * 16;
        if (cb >= QKV3) continue;
        int c2 = cb + (lane & 15);
        #pragma unroll
        for (int m = 0; m < 4; ++m) {
            int r0 = bm + wm * 64 + m * 16 + ((lane >> 4) << 2);
            #pragma unroll
            for (int j = 0; j < 4; ++j) {
                int r = r0 + j;
                if (r < n) outb[(size_t)r * QKV3 + c2] = acc[m][q][j];
            }
        }
    }
}

__global__ void qkv_reduce(const float* __restrict__ part,
                           const float* __restrict__ bq,
                           const float* __restrict__ bk,
                           const float* __restrict__ bv,
                           float* __restrict__ qkvAll, int l) {
    int idx = blockIdx.x * 256 + threadIdx.x;
    if (idx >= 420000) return;
    int scale, base;
    if (idx < 240000) { scale = 0; base = 0; }
    else if (idx < 360000) { scale = 1; base = 240000; }
    else { scale = 2; base = 360000; }
    int rowrem = (idx - base) % QKV3;
    int which = rowrem / QKVN;
    int col = rowrem - which * QKVN;
    float v = part[idx] + part[QSP + idx]
            + part[2 * QSP + idx] + part[3 * QSP + idx];
    v += ((which == 0) ? bq : (which == 1 ? bk : bv))[(size_t)(l * 3 + scale) * QKVN + col];
    qkvAll[idx] = v;
}

// ======================= attention: 64-key-split flash =====================
__global__ __launch_bounds__(256, 2) void attn_split(
        const float* __restrict__ qkvAll, float* __restrict__ oPart,
        float* __restrict__ mPart, float* __restrict__ lPart) {
    int z = blockIdx.z;
    int scale, sp;
    if (z < 8)       { scale = 0; sp = z; }
    else if (z < 12) { scale = 1; sp = z - 8; }
    else             { scale = 2; sp = z - 12; }
    int n = NN >> scale;
    int qt = blockIdx.x;
    if (qt * 64 >= n) return;
    int hh = blockIdx.y;
    int ks = sp * 64;
    int ke = min(n, ks + 64);
    const float* qkv = qkvAll + (scale == 0 ? 0 : (scale == 1 ? 240000 : 360000));
    int rowb = (scale == 0 ? 0 : (scale == 1 ? 500 : 750));

    int tid = threadIdx.x;
    int kg = tid & 7, qq = tid >> 3;
    int q0 = qt * 64 + qq, q1 = q0 + 32;
    bool ok0 = q0 < n, ok1 = q1 < n;

    float qa[32], qb[32];
    {
        const float* p0 = qkv + (size_t)(ok0 ? q0 : 0) * QKV3 + hh * KDD;
        const float* p1 = qkv + (size_t)(ok1 ? q1 : 0) * QKV3 + hh * KDD;
        #pragma unroll
        for (int c4 = 0; c4 < 8; ++c4) {
            float4 v0 = *(const float4*)(p0 + c4 * 4);
            float4 v1 = *(const float4*)(p1 + c4 * 4);
            qa[c4 * 4] = v0.x; qa[c4 * 4 + 1] = v0.y; qa[c4 * 4 + 2] = v0.z; qa[c4 * 4 + 3] = v0.w;
            qb[c4 * 4] = v1.x; qb[c4 * 4 + 1] = v1.y; qb[c4 * 4 + 2] = v1.z; qb[c4 * 4 + 3] = v1.w;
        }
    }

    __shared__ float Ks[64][36];
    __shared__ float Vs[64][36];
    float o0[32], o1[32];
    #pragma unroll
    for (int c = 0; c < 32; ++c) { o0[c] = 0.f; o1[c] = 0.f; }
    float m0 = -1e30f, m1 = -1e30f, l0 = 0.f, l1 = 0.f;

    int srow = tid >> 2, scol = tid & 3;

    {
        int kc = ks;
        int krow = kc + srow;
        bool ok = krow < ke;
        const float* kp = qkv + (size_t)(ok ? krow : 0) * QKV3 + QKVN + hh * KDD;
        #pragma unroll
        for (int half = 0; half < 2; ++half) {
            int cc = (half * 4 + scol) * 4;
            float4 kv = ok ? *(const float4*)(kp + cc) : make_float4(0.f, 0.f, 0.f, 0.f);
            float4 vv = ok ? *(const float4*)(kp + QKVN + cc) : make_float4(0.f, 0.f, 0.f, 0.f);
            Ks[srow][cc] = kv.x; Ks[srow][cc + 1] = kv.y; Ks[srow][cc + 2] = kv.z; Ks[srow][cc + 3] = kv.w;
            Vs[srow][cc] = vv.x; Vs[srow][cc + 1] = vv.y; Vs[srow][cc + 2] = vv.z; Vs[srow][cc + 3] = vv.w;
        }
        __syncthreads();

        float p0[8], p1[8];
        float cm = -1e30f;
        #pragma unroll
        for (int jj = 0; jj < 8; ++jj) {
            int j = jj * 8 + kg;
            float s0 = 0.f, s1 = 0.f;
            #pragma unroll
            for (int c4 = 0; c4 < 8; ++c4) {
                float4 kv = *(const float4*)&Ks[j][c4 * 4];
                s0 += qa[c4 * 4] * kv.x + qa[c4 * 4 + 1] * kv.y
                    + qa[c4 * 4 + 2] * kv.z + qa[c4 * 4 + 3] * kv.w;
                s1 += qb[c4 * 4] * kv.x + qb[c4 * 4 + 1] * kv.y
                    + qb[c4 * 4 + 2] * kv.z + qb[c4 * 4 + 3] * kv.w;
            }
            s0 *= 0.17677669529663687f;
            s1 *= 0.17677669529663687f;
            if (kc + j >= ke) { s0 = -1e30f; s1 = -1e30f; }
            p0[jj] = s0; p1[jj] = s1;
            cm = fmaxf(cm, fmaxf(s0, s1));
        }
        cm = fmaxf(cm, __shfl_xor(cm, 1));
        cm = fmaxf(cm, __shfl_xor(cm, 2));
        cm = fmaxf(cm, __shfl_xor(cm, 4));

        m0 = cm; m1 = cm;
        #pragma unroll
        for (int jj = 0; jj < 8; ++jj) {
            p0[jj] = expf(p0[jj] - cm); l0 += p0[jj];
            p1[jj] = expf(p1[jj] - cm); l1 += p1[jj];
        }
        #pragma unroll
        for (int jj = 0; jj < 8; ++jj) {
            int j = jj * 8 + kg;
            float w0 = p0[jj], w1 = p1[jj];
            #pragma unroll
            for (int c4 = 0; c4 < 8; ++c4) {
                float4 vv = *(const float4*)&Vs[j][c4 * 4];
                o0[c4 * 4]     += w0 * vv.x; o0[c4 * 4 + 1] += w0 * vv.y;
                o0[c4 * 4 + 2] += w0 * vv.z; o0[c4 * 4 + 3] += w0 * vv.w;
                o1[c4 * 4]     += w1 * vv.x; o1[c4 * 4 + 1] += w1 * vv.y;
                o1[c4 * 4 + 2] += w1 * vv.z; o1[c4 * 4 + 3] += w1 * vv.w;
            }
        }
    }
    #pragma unroll
    for (int st = 1; st < 8; st <<= 1) {
        l0 += __shfl_xor(l0, st);
        l1 += __shfl_xor(l1, st);
        #pragma unroll
        for (int c = 0; c < 32; ++c) {
            o0[c] += __shfl_xor(o0[c], st);
            o1[c] += __shfl_xor(o1[c], st);
        }
    }
    if (kg == 0) {
        float* ob = oPart + (size_t)sp * OSZ;
        if (ok0) {
            int r = rowb + q0;
            float* op = ob + (size_t)r * QKVN + hh * KDD;
            #pragma unroll
            for (int c4 = 0; c4 < 8; ++c4) {
                float4 v; v.x = o0[c4*4]; v.y = o0[c4*4+1]; v.z = o0[c4*4+2]; v.w = o0[c4*4+3];
                *(float4*)(op + c4 * 4) = v;
            }
            mPart[sp * MLSZ + r * HSC + hh] = m0;
            lPart[sp * MLSZ + r * HSC + hh] = l0;
        }
        if (ok1) {
            int r = rowb + q1;
            float* op = ob + (size_t)r * QKVN + hh * KDD;
            #pragma unroll
            for (int c4 = 0; c4 < 8; ++c4) {
                float4 v; v.x = o1[c4*4]; v.y = o1[c4*4+1]; v.z = o1[c4*4+2]; v.w = o1[c4*4+3];
                *(float4*)(op + c4 * 4) = v;
            }
            mPart[sp * MLSZ + r * HSC + hh] = m1;
            lPart[sp * MLSZ + r * HSC + hh] = l1;
        }
    }
}

// ns = 8 >> scale partial slices; writes oAll at offsets 0/80000/120000
__global__ void attn_combine(const float* __restrict__ oPart,
                             const float* __restrict__ mPart,
                             const float* __restrict__ lPart,
                             float* __restrict__ oAll) {
    int idx = blockIdx.x * 256 + threadIdx.x;
    if (idx >= OSZ) return;
    int rh = idx >> 5;
    int r = rh / HSC, hh = rh - r * HSC;
    int scale = (r < 500) ? 0 : (r < 750 ? 1 : 2);
    int ns = 8 >> scale;
    float M = -1e30f;
    for (int s = 0; s < ns; ++s) M = fmaxf(M, mPart[s * MLSZ + r * HSC + hh]);
    float L = 0.f, val = 0.f;
    for (int s = 0; s < ns; ++s) {
        float wgt = expf(mPart[s * MLSZ + r * HSC + hh] - M);
        L += wgt * lPart[s * MLSZ + r * HSC + hh];
        val += wgt * oPart[(size_t)s * OSZ + idx];
    }
    oAll[idx] = val / L;
}

// ======================= comb via W2c (gather oAll, K=480 padded 576) ======
// grid (8, 4, 9): z = sp in [0,9): si = sp/3, 64-k chunk (sp%3) of the
// 192-padded per-scale K block. A row gather: row>>si (upsample-by-read).
// W2c rows 160..191 are zeros -> no A-side tail mask needed; A k-address
// clamped to 156 so duplicate (not OOB) elements pair with the zero rows.
__global__ __launch_bounds__(256, 2) void comb_gather(
        const float* __restrict__ oAll, const float* __restrict__ w2c,
        float* __restrict__ part, int l) {
    int sp = blockIdx.z;
    int si = (sp >= 6) ? 2 : (sp >= 3 ? 1 : 0);
    int kseg = (sp - si * 3) << 6;                 // 0,64,128
    int bm = blockIdx.y * BM, bn = blockIdx.x * BN;
    int tid = threadIdx.x;
    const int soff = (si == 0) ? 0 : (si == 1 ? 80000 : 120000);
    const float* Bcol = w2c + (size_t)(l * 3 + si) * W2CL
                      + (size_t)kseg * DD + bn + (tid & 15) * 4;

    __shared__ __align__(16) unsigned short As[128 * 64];
    __shared__ __align__(16) unsigned short Bs[64 * 64];
    const int ar4 = tid >> 2, akq = (tid & 3) * 16;
    const int bkq = (tid >> 4) * 4, bn4 = tid & 15;
    const int lane = tid & 63, wid = tid >> 6;
    const int wm = wid >> 1, wn = wid & 1;

    f32x4 acc[4][2];
    MACC_INIT(acc);
    float4 aR[2][4], bR[4];

    // single-chunk stage (branch-free)
    #pragma unroll
    for (int p = 0; p < 2; ++p) {
        int row = min(bm + ar4 + p * 64, NN - 1);
        const float* ap = oAll + soff + (size_t)(row >> si) * QKVN;
        #pragma unroll
        for (int i = 0; i < 4; ++i) {
            int kk = kseg + akq + i * 4;
            int kg2 = min(kk, QKVN - 4);           // clamp; pad rows of B are 0
            aR[p][i] = *(const float4*)(ap + kg2);
        }
    }
    #pragma unroll
    for (int i = 0; i < 4; ++i)
        bR[i] = *(const float4*)(Bcol + (size_t)(bkq + i) * DD);

    __syncthreads();
    CHUNK_LDS_WRITE();
    __syncthreads();
    CHUNK_MFMA();

    float* pz = part + (size_t)sp * NN * DD;
    #pragma unroll
    for (int q = 0; q < 2; ++q) {
        int c2 = bn + wn * 32 + q * 16 + (lane & 15);
        #pragma unroll
        for (int m = 0; m < 4; ++m) {
            int r0 = bm + wm * 64 + m * 16 + ((lane >> 4) << 2);
            #pragma unroll
            for (int j = 0; j < 4; ++j) {
                int r = r0 + j;
                if (r < NN) pz[(size_t)r * DD + c2] = acc[m][q][j];
            }
        }
    }
}

// ======================= W1 partial (k-split S=4) ==========================
__global__ __launch_bounds__(256, 2) void w1_part(
        const float* __restrict__ h, const float* __restrict__ W1,
        float* __restrict__ part) {
    int sp = blockIdx.z;
    int bm = blockIdx.y * BM, bn = blockIdx.x * BN;
    int tid = threadIdx.x;
    const float* Bcol = W1 + bn + (tid & 15) * 4;
    f32x4 acc[4][2];
    MACC_INIT(acc);
    mfma_core<1, 0>(h, DD, Bcol, FF, NN, bm, sp * 128, 2, DD, acc);

    float* pz = part + (size_t)sp * NN * FF;
    int lane = tid & 63, wid = tid >> 6, wm = wid >> 1, wn = wid & 1;
    #pragma unroll
    for (int q = 0; q < 2; ++q) {
        int c2 = bn + wn * 32 + q * 16 + (lane & 15);
        #pragma unroll
        for (int m = 0; m < 4; ++m) {
            int r0 = bm + wm * 64 + m * 16 + ((lane >> 4) << 2);
            #pragma unroll
            for (int j = 0; j < 4; ++j) {
                int r = r0 + j;
                if (r < NN) pz[(size_t)r * FF + c2] = acc[m][q][j];
            }
        }
    }
}

__global__ void w1_reduce(const float* __restrict__ part,
                          const float* __restrict__ b1, float* __restrict__ f) {
    int idx = blockIdx.x * 256 + threadIdx.x;
    if (idx >= NN * FF) return;
    float v = part[idx] + part[NN * FF + idx]
            + part[2 * NN * FF + idx] + part[3 * NN * FF + idx];
    f[idx] = gelu_exact(v + b1[idx & (FF - 1)]);
}

// ======================= W2 partial (k-split S=16) =========================
__global__ __launch_bounds__(256, 2) void w2_part(
        const float* __restrict__ f, const float* __restrict__ W2,
        float* __restrict__ part) {
    int sp = blockIdx.z;
    int bm = blockIdx.y * BM, bn = blockIdx.x * BN;
    int tid = threadIdx.x;
    const float* Bcol = W2 + bn + (tid & 15) * 4;
    f32x4 acc[4][2];
    MACC_INIT(acc);
    mfma_core<1, 0>(f, FF, Bcol, DD, NN, bm, sp * 128, 2, FF, acc);

    float* pz = part + (size_t)sp * NN * DD;
    int lane = tid & 63, wid = tid >> 6, wm = wid >> 1, wn = wid & 1;
    #pragma unroll
    for (int q = 0; q < 2; ++q) {
        int c2 = bn + wn * 32 + q * 16 + (lane & 15);
        #pragma unroll
        for (int m = 0; m < 4; ++m) {
            int r0 = bm + wm * 64 + m * 16 + ((lane >> 4) << 2);
            #pragma unroll
            for (int j = 0; j < 4; ++j) {
                int r = r0 + j;
                if (r < NN) pz[(size_t)r * DD + c2] = acc[m][q][j];
            }
        }
    }
}

// ======================= fused reduce + bias + residual + LN ===============
__global__ void reduce_add_ln(const float* __restrict__ part, int S,
                              const float* __restrict__ bias,
                              float* __restrict__ h,
                              const float* __restrict__ gw,
                              const float* __restrict__ bw) {
    int row = blockIdx.x, t = threadIdx.x;
    size_t idx = (size_t)row * DD + t;
    float x = h[idx] + bias[t];
    for (int s = 0; s < S; ++s) x += part[(size_t)s * NN * DD + idx];
    int lane = t & 63, wv = t >> 6;
    __shared__ float s1[8], s2[8];
    __shared__ float mb[2];
    float sum = x, sq = x * x;
    for (int off = 32; off; off >>= 1) {
        sum += __shfl_down(sum, off);
        sq  += __shfl_down(sq,  off);
    }
    if (lane == 0) { s1[wv] = sum; s2[wv] = sq; }
    __syncthreads();
    if (t == 0) {
        float a = 0.f, b = 0.f;
        for (int i = 0; i < 8; ++i) { a += s1[i]; b += s2[i]; }
        float mean = a / (float)DD;
        float var = b / (float)DD - mean * mean;
        mb[0] = mean;
        mb[1] = rsqrtf(var + LNEPS);
    }
    __syncthreads();
    h[idx] = (x - mb[0]) * mb[1] * gw[t] + bw[t];
}

// ======================= head =======================
__global__ void col_mean_part(const float* __restrict__ h, float* __restrict__ partial) {
    int col = blockIdx.x * 256 + threadIdx.x;
    int r0 = blockIdx.y * 20;
    float s = 0.f;
    #pragma unroll
    for (int r = 0; r < 20; ++r) s += h[(size_t)(r0 + r) * DD + col];
    partial[(size_t)blockIdx.y * DD + col] = s;
}

__global__ void head_kernel(const float* __restrict__ partial,
                            const float* __restrict__ hw,
                            const float* __restrict__ hb, float* __restrict__ out) {
    __shared__ float gs[DD];
    __shared__ float r[4];
    __shared__ float bmx, bsum;
    int t = threadIdx.x;
    for (int d = t; d < DD; d += 256) {
        float s = 0.f;
        #pragma unroll
        for (int p = 0; p < 25; ++p) s += partial[(size_t)p * DD + d];
        gs[d] = s / (float)NN;
    }
    __syncthreads();
    float acc = hb[t];
    #pragma unroll 16
    for (int d = 0; d < DD; ++d) acc += gs[d] * hw[(size_t)d * NC + t];
    int lane = t & 63, wv = t >> 6;
    float mx = acc;
    for (int off = 32; off; off >>= 1) mx = fmaxf(mx, __shfl_down(mx, off));
    if (lane == 0) r[wv] = mx;
    __syncthreads();
    if (t == 0) bmx = fmaxf(fmaxf(r[0], r[1]), fmaxf(r[2], r[3]));
    __syncthreads();
    float e = expf(acc - bmx);
    float s = e;
    for (int off = 32; off; off >>= 1) s += __shfl_down(s, off);
    if (lane == 0) r[wv] = s;
    __syncthreads();
    if (t == 0) bsum = 1.f / (r[0] + r[1] + r[2] + r[3]);
    __syncthreads();
    float pv = e * bsum;
    for (int b = 0; b < NB; ++b) out[(size_t)b * NC + t] = pv;
}

extern "C" void kernel_launch(void* const* d_in, const int* in_sizes, int n_in,
                              void* d_out, int out_size, void* d_ws, size_t ws_size,
                              hipStream_t stream) {
    const float* ln_in_b = (const float*)d_in[2];
    const float* patch_W = (const float*)d_in[3];
    const float* patch_b = (const float*)d_in[4];
    const float* pos_emb = (const float*)d_in[5];
    const float* Wq = (const float*)d_in[6];
    const float* bq = (const float*)d_in[7];
    const float* Wk = (const float*)d_in[8];
    const float* bk = (const float*)d_in[9];
    const float* Wv = (const float*)d_in[10];
    const float* bv = (const float*)d_in[11];
    const float* Wo = (const float*)d_in[12];
    const float* bo = (const float*)d_in[13];
    const float* Wc = (const float*)d_in[14];
    const float* bc = (const float*)d_in[15];
    const float* ln1_g = (const float*)d_in[16];
    const float* ln1_b = (const float*)d_in[17];
    const float* W1 = (const float*)d_in[18];
    const float* b1 = (const float*)d_in[19];
    const float* W2 = (const float*)d_in[20];
    const float* b2 = (const float*)d_in[21];
    const float* ln2_g = (const float*)d_in[22];
    const float* ln2_b = (const float*)d_in[23];
    const float* head_W = (const float*)d_in[24];
    const float* head_b = (const float*)d_in[25];
    float* out = (float*)d_out;

    // workspace (floats). part region aliases: qkvP (dead after qkv_reduce),
    // then oPart/mPart/lPart (dead after attn_combine), then comb/w1/w2
    // partials.
    float* ws = (float*)d_ws;
    float* h      = ws;                  // 256000
    float* csum   = h + 256000;          // 1024
    float* qkvAll = csum + 1024;         // 420000
    float* oAll   = qkvAll + 420000;     // 140000
    float* f      = oAll + 140000;       // 1024000
    float* part   = f + 1024000;         // 4194304
    float* headp  = part + 4194304;      // 12800
    float* w2c    = headp + 12800;       // 18*98304 = 1769472
    float* bconst = w2c + 1769472;       // 6*512 = 3072
    float* bpart  = bconst + 3072;       // 144*512 = 73728
    float* qkvP   = part;                // 4*420000 = 1680000
    float* oPart  = part + 1680000;      // 8*140000 = 1120000
    float* mPart  = oPart + 1120000;     // 8*4384
    float* lPart  = mPart + 8 * MLSZ;    // 8*4384

    colsum_kernel<<<1, 512, 0, stream>>>(patch_W, csum);
    init_h<<<(NN * DD + 255) / 256, 256, 0, stream>>>(csum, patch_b, pos_emb, ln_in_b, h);
    w2c_pre<<<dim3(8, 2, 18), 256, 0, stream>>>(Wo, Wc, w2c);
    bconst_part<<<dim3(18, 8), 256, 0, stream>>>(bo, Wc, bpart);
    bconst_fin<<<NL, DD, 0, stream>>>(bpart, bc, bconst);

    for (int l = 0; l < NL; ++l) {
        qkv_part<<<dim3(8, 4, 12), 256, 0, stream>>>(h, Wq, Wk, Wv, qkvP, l);
        qkv_reduce<<<(420000 + 255) / 256, 256, 0, stream>>>(qkvP, bq, bk, bv, qkvAll, l);
        attn_split<<<dim3(8, HSC, 14), 256, 0, stream>>>(qkvAll, oPart, mPart, lPart);
        attn_combine<<<(OSZ + 255) / 256, 256, 0, stream>>>(oPart, mPart, lPart, oAll);
        comb_gather<<<dim3(8, 4, 9), 256, 0, stream>>>(oAll, w2c, part, l);
        reduce_add_ln<<<NN, DD, 0, stream>>>(part, 9, bconst + (size_t)l * DD, h,
                                             ln1_g + (size_t)l * DD, ln1_b + (size_t)l * DD);
        w1_part<<<dim3(32, 4, 4), 256, 0, stream>>>(
            h, W1 + (size_t)l * DD * FF, part);
        w1_reduce<<<(NN * FF + 255) / 256, 256, 0, stream>>>(
            part, b1 + (size_t)l * FF, f);
        w2_part<<<dim3(8, 4, 16), 256, 0, stream>>>(f, W2 + (size_t)l * FF * DD, part);
        reduce_add_ln<<<NN, DD, 0, stream>>>(part, 16, b2 + (size_t)l * DD, h,
                                             ln2_g + (size_t)l * DD, ln2_b + (size_t)l * DD);
    }
    col_mean_part<<<dim3(2, 25), 256, 0, stream>>>(h, headp);
    head_kernel<<<1, 256, 0, stream>>>(headp, head_W, head_b, out);
}